// Round 5
// baseline (546.676 us; speedup 1.0000x reference)
//
#include <hip/hip_runtime.h>

#define N_NODES 50000
#define N_EDGES 800000
#define DIM 128
#define OUTD 47
#define NBK 196                          // dst buckets of 256 nodes
#define EPB 4096                         // edges per histogram/bin block
#define NBIN ((N_EDGES + EPB - 1) / EPB) // 196
#define XCVT_NB (N_NODES * DIM / 8 / 256) // 3125 blocks, 8 elems/thread
#define WFNB 19                          // weight-fragment tiles: 8 + 8 + 3

typedef __attribute__((ext_vector_type(8))) short v8s;
typedef __attribute__((ext_vector_type(8))) unsigned short v8u;
typedef __attribute__((ext_vector_type(4))) float v4f;
typedef __attribute__((ext_vector_type(2))) float v2f;

static __device__ __forceinline__ unsigned short f2bf(float f) {
    union { float f; unsigned int u; } v; v.f = f;
    unsigned int x = v.u;
    return (unsigned short)((x + 0x7fffu + ((x >> 16) & 1u)) >> 16); // RNE
}
static __device__ __forceinline__ unsigned char f2fp8(float f) {
    unsigned int pk = __builtin_amdgcn_cvt_pk_fp8_f32(f, f, 0, false);
    return (unsigned char)(pk & 0xffu);
}

// ---------------- prep: x->bf16+fp8 | per-block bucket hist partials | weight fragment cvt ----------------
// Weights are emitted PRE-SWIZZLED into MFMA B-fragment order:
//   frag(t, c): lane l holds W[j = t*16 + (l&15)][k = c*32 + (l>>4)*8 + i], i=0..7 (bf16 x8, 16B)
//   stored at ob[((t*8 + c)*64 + l)*8 + i]  -> a wave's fragment read is 1KB contiguous.
__global__ __launch_bounds__(256) void k_prep(const float* __restrict__ x,
                                              unsigned short* __restrict__ xb,
                                              unsigned int* __restrict__ x8,
                                              const int* __restrict__ dst,
                                              int* __restrict__ parts,
                                              const float* __restrict__ ws1, const float* __restrict__ wn1,
                                              const float* __restrict__ ws2, const float* __restrict__ wn2,
                                              const float* __restrict__ ws3, const float* __restrict__ wn3,
                                              unsigned short* __restrict__ wf1,
                                              unsigned short* __restrict__ wf2,
                                              unsigned short* __restrict__ wf3) {
    __shared__ int hist[NBK];
    const int bx = blockIdx.x, tid = threadIdx.x;
    if (bx < XCVT_NB) {
        int i = bx * 256 + tid; // 8 elems per thread
        float4 v0 = ((const float4*)x)[i * 2];
        float4 v1 = ((const float4*)x)[i * 2 + 1];
        ushort4 o0, o1;
        o0.x = f2bf(v0.x); o0.y = f2bf(v0.y); o0.z = f2bf(v0.z); o0.w = f2bf(v0.w);
        o1.x = f2bf(v1.x); o1.y = f2bf(v1.y); o1.z = f2bf(v1.z); o1.w = f2bf(v1.w);
        ((ushort4*)xb)[i * 2] = o0;
        ((ushort4*)xb)[i * 2 + 1] = o1;
        unsigned int a = __builtin_amdgcn_cvt_pk_fp8_f32(v0.x, v0.y, 0, false);
        a = __builtin_amdgcn_cvt_pk_fp8_f32(v0.z, v0.w, a, true);
        unsigned int b = __builtin_amdgcn_cvt_pk_fp8_f32(v1.x, v1.y, 0, false);
        b = __builtin_amdgcn_cvt_pk_fp8_f32(v1.z, v1.w, b, true);
        uint2 o; o.x = a; o.y = b;
        ((uint2*)x8)[i] = o;
    } else if (bx < XCVT_NB + NBIN) {
        const int j = bx - XCVT_NB;
        for (int i = tid; i < NBK; i += 256) hist[i] = 0;
        __syncthreads();
        const int e0 = j * EPB;
        const int ecnt = min(EPB, N_EDGES - e0);
        for (int r = tid; r < ecnt; r += 256)
            atomicAdd(&hist[dst[e0 + r] >> 8], 1); // LDS only
        __syncthreads();
        for (int i = tid; i < NBK; i += 256) parts[j * NBK + i] = hist[i];
    } else {
        int b2 = bx - XCVT_NB - NBIN; // fragment tile
        const float *sw, *nw; unsigned short* ob; int t, J;
        if (b2 < 8)       { sw = ws1; nw = wn1; ob = wf1; t = b2;      J = DIM; }
        else if (b2 < 16) { sw = ws2; nw = wn2; ob = wf2; t = b2 - 8;  J = DIM; }
        else              { sw = ws3; nw = wn3; ob = wf3; t = b2 - 16; J = OUTD; }
        const int lane = tid & 63, cp = tid >> 6;
        const int j = t * 16 + (lane & 15);
        const int kb = (lane >> 4) * 8;
        #pragma unroll
        for (int c2 = 0; c2 < 2; ++c2) {
            int c = cp * 2 + c2;
            int k0 = c * 32 + kb;
            v8u o;
            #pragma unroll
            for (int i = 0; i < 8; ++i) {
                int k = k0 + i;
                float v = 0.f;
                if (j < J) v = (k < DIM) ? sw[j * DIM + k] : nw[j * DIM + (k - DIM)];
                o[i] = f2bf(v);
            }
            *(v8u*)(ob + ((size_t)((t * 8 + c) * 64 + lane)) * 8) = o;
        }
    }
}

// ---------------- bin: local column-prefix of parts -> bases; place edges (LDS atomics only) ----------------
__global__ __launch_bounds__(256) void k_bin(const int* __restrict__ src,
                                             const int* __restrict__ dst,
                                             const int* __restrict__ parts,
                                             unsigned int* __restrict__ packed) {
    __shared__ int s[256], gb[NBK], cnt[NBK];
    const int t = threadIdx.x;
    const int j = blockIdx.x;
    int ct = 0, cp = 0;
    for (int i = 0; i < NBIN; ++i) {
        int v = (t < NBK) ? parts[i * NBK + t] : 0;
        if (i == j) cp = ct;
        ct += v;
    }
    s[t] = ct;
    __syncthreads();
    for (int off = 1; off < 256; off <<= 1) {
        int u = (t >= off) ? s[t - off] : 0;
        __syncthreads();
        s[t] += u;
        __syncthreads();
    }
    if (t < NBK) { gb[t] = (s[t] - ct) + cp; cnt[t] = 0; } // bucket base + own-block offset
    __syncthreads();
    const int e0 = j * EPB;
    const int ecnt = min(EPB, N_EDGES - e0);
    for (int r = t; r < ecnt; r += 256) {
        int sv = src[e0 + r], d = dst[e0 + r];
        int b = d >> 8;
        int loc = atomicAdd(&cnt[b], 1); // LDS
        packed[gb[b] + loc] = ((unsigned int)sv << 8) | (unsigned int)(d & 255);
    }
}

// ---------------- place: local bucket scan + per-node hist -> row_ptr, scatter src_sorted ----------------
__global__ __launch_bounds__(256) void k_place(const unsigned int* __restrict__ packed,
                                               const int* __restrict__ parts,
                                               int* __restrict__ row_ptr,
                                               int* __restrict__ src_sorted) {
    __shared__ int s[256], baseL[NBK], totL[NBK];
    __shared__ int hist[256], cur[256];
    const int b = blockIdx.x, t = threadIdx.x;
    int ct = 0;
    for (int i = 0; i < NBIN; ++i)
        ct += (t < NBK) ? parts[i * NBK + t] : 0;
    s[t] = ct;
    hist[t] = 0;
    __syncthreads();
    for (int off = 1; off < 256; off <<= 1) {
        int u = (t >= off) ? s[t - off] : 0;
        __syncthreads();
        s[t] += u;
        __syncthreads();
    }
    if (t < NBK) { baseL[t] = s[t] - ct; totL[t] = ct; }
    __syncthreads();
    const int base = baseL[b], cb = totL[b];
    for (int i = t; i < cb; i += 256)
        atomicAdd(&hist[packed[base + i] & 255u], 1); // LDS, ~16 avg per counter
    __syncthreads();
    int v = hist[t];
    s[t] = v;
    __syncthreads();
    for (int off = 1; off < 256; off <<= 1) {
        int u = (t >= off) ? s[t - off] : 0;
        __syncthreads();
        s[t] += u;
        __syncthreads();
    }
    int excl = base + s[t] - v;
    int node = b * 256 + t;
    if (node < N_NODES) row_ptr[node] = excl;
    if (b == NBK - 1 && t == 255) row_ptr[N_NODES] = base + cb; // == N_EDGES
    cur[t] = excl;
    __syncthreads();
    for (int i = t; i < cb; i += 256) {
        unsigned int pkt = packed[base + i];
        int pos = atomicAdd(&cur[pkt & 255u], 1);
        src_sorted[pos] = (int)(pkt >> 8); // lands in this bucket's ~16KB region
    }
}

// ---------------- fused layer: self-load + mean-aggregate -> LDS A-tile, then MFMA GEMM ----------------
// Gather is latency-bound on per-wave MLP: process TWO node-passes concurrently (8 gathers +
// 8 srcs loads in flight per wave instead of 4). Accumulation order per node unchanged.
static __device__ __forceinline__ void acc16(v2f* acc, uint4 u) {
    acc[0] += __builtin_amdgcn_cvt_pk_f32_fp8(u.x, false);
    acc[1] += __builtin_amdgcn_cvt_pk_f32_fp8(u.x, true);
    acc[2] += __builtin_amdgcn_cvt_pk_f32_fp8(u.y, false);
    acc[3] += __builtin_amdgcn_cvt_pk_f32_fp8(u.y, true);
    acc[4] += __builtin_amdgcn_cvt_pk_f32_fp8(u.z, false);
    acc[5] += __builtin_amdgcn_cvt_pk_f32_fp8(u.z, true);
    acc[6] += __builtin_amdgcn_cvt_pk_f32_fp8(u.w, false);
    acc[7] += __builtin_amdgcn_cvt_pk_f32_fp8(u.w, true);
}

template <int NT, bool RELU, bool OUTBF>
__global__ __launch_bounds__(256, 4) void k_layer(const unsigned short* __restrict__ Ab,
                                                  const unsigned char* __restrict__ g8,
                                                  const int* __restrict__ row_ptr,
                                                  const int* __restrict__ srcs,
                                                  const unsigned short* __restrict__ Wf,
                                                  const float* __restrict__ bias,
                                                  void* __restrict__ out,
                                                  unsigned char* __restrict__ out8,
                                                  int outdim) {
    __shared__ unsigned short Alds[64 * 256]; // 32 KB: [row][0..128)=self, [128..256)=mean, XOR-swizzled
    const int tid = threadIdx.x;
    const int m0 = blockIdx.x * 64;
    // ---- self half -> LDS ----
    #pragma unroll
    for (int i = 0; i < 4; ++i) {
        int t = tid + 256 * i;           // 0..1023
        int row = t >> 4, ch = t & 15;   // 64 rows x 16 chunks of 8 shorts
        int node = m0 + row; if (node >= N_NODES) node = N_NODES - 1;
        v8u v = *(const v8u*)(Ab + (size_t)node * DIM + ch * 8);
        *(v8u*)(Alds + row * 256 + ((ch * 8) ^ ((row & 7) * 8))) = v;
    }
    // ---- mean half: gather fp8 rows; two concurrent node-passes per wave ----
    const int lane = tid & 63, wv = tid >> 6;
    const int gg = lane & 7;          // 8 lanes span the 128B row, 16B each
    const int sub = (lane >> 3) & 1;  // which edge of a pair this half handles
    const int ns = lane >> 4;         // node slot within wave
    #pragma unroll
    for (int pp = 0; pp < 2; ++pp) {
        const int rowA = wv * 16 + pp * 8 + ns; // pass 2*pp
        const int rowB = rowA + 4;              // pass 2*pp+1
        const int nA = m0 + rowA, nB = m0 + rowB;
        int stA = 0, enA = 0, stB = 0, enB = 0;
        if (nA < N_NODES) { stA = row_ptr[nA]; enA = row_ptr[nA + 1]; }
        if (nB < N_NODES) { stB = row_ptr[nB]; enB = row_ptr[nB + 1]; }
        v2f gaA[8] = {}, gaB[8] = {};
        int eA = stA, eB = stB;
        while ((eA + 8 <= enA) || (eB + 8 <= enB)) {
            const bool dA = (eA + 8 <= enA), dB = (eB + 8 <= enB);
            int a0, a1, a2, a3, b0, b1, b2, b3;
            if (dA) { a0 = srcs[eA + sub]; a1 = srcs[eA + 2 + sub]; a2 = srcs[eA + 4 + sub]; a3 = srcs[eA + 6 + sub]; }
            if (dB) { b0 = srcs[eB + sub]; b1 = srcs[eB + 2 + sub]; b2 = srcs[eB + 4 + sub]; b3 = srcs[eB + 6 + sub]; }
            uint4 uA0, uA1, uA2, uA3, uB0, uB1, uB2, uB3;
            if (dA) {
                uA0 = *(const uint4*)(g8 + (size_t)a0 * DIM + gg * 16);
                uA1 = *(const uint4*)(g8 + (size_t)a1 * DIM + gg * 16);
                uA2 = *(const uint4*)(g8 + (size_t)a2 * DIM + gg * 16);
                uA3 = *(const uint4*)(g8 + (size_t)a3 * DIM + gg * 16);
            }
            if (dB) {
                uB0 = *(const uint4*)(g8 + (size_t)b0 * DIM + gg * 16);
                uB1 = *(const uint4*)(g8 + (size_t)b1 * DIM + gg * 16);
                uB2 = *(const uint4*)(g8 + (size_t)b2 * DIM + gg * 16);
                uB3 = *(const uint4*)(g8 + (size_t)b3 * DIM + gg * 16);
            }
            if (dA) { acc16(gaA, uA0); acc16(gaA, uA1); acc16(gaA, uA2); acc16(gaA, uA3); eA += 8; }
            if (dB) { acc16(gaB, uB0); acc16(gaB, uB1); acc16(gaB, uB2); acc16(gaB, uB3); eB += 8; }
        }
        // tails (A/B interleaved for MLP)
        {
            const bool dA = (eA + 4 <= enA), dB = (eB + 4 <= enB);
            int a0, a1, b0, b1;
            if (dA) { a0 = srcs[eA + sub]; a1 = srcs[eA + 2 + sub]; }
            if (dB) { b0 = srcs[eB + sub]; b1 = srcs[eB + 2 + sub]; }
            uint4 uA0, uA1, uB0, uB1;
            if (dA) {
                uA0 = *(const uint4*)(g8 + (size_t)a0 * DIM + gg * 16);
                uA1 = *(const uint4*)(g8 + (size_t)a1 * DIM + gg * 16);
            }
            if (dB) {
                uB0 = *(const uint4*)(g8 + (size_t)b0 * DIM + gg * 16);
                uB1 = *(const uint4*)(g8 + (size_t)b1 * DIM + gg * 16);
            }
            if (dA) { acc16(gaA, uA0); acc16(gaA, uA1); eA += 4; }
            if (dB) { acc16(gaB, uB0); acc16(gaB, uB1); eB += 4; }
        }
        {
            const bool dA = (eA + 2 <= enA), dB = (eB + 2 <= enB);
            int a0, b0;
            if (dA) a0 = srcs[eA + sub];
            if (dB) b0 = srcs[eB + sub];
            uint4 uA0, uB0;
            if (dA) uA0 = *(const uint4*)(g8 + (size_t)a0 * DIM + gg * 16);
            if (dB) uB0 = *(const uint4*)(g8 + (size_t)b0 * DIM + gg * 16);
            if (dA) { acc16(gaA, uA0); eA += 2; }
            if (dB) { acc16(gaB, uB0); eB += 2; }
        }
        {
            const bool dA = (eA < enA) && (sub == 0), dB = (eB < enB) && (sub == 0);
            int a0, b0;
            if (dA) a0 = srcs[eA];
            if (dB) b0 = srcs[eB];
            uint4 uA0, uB0;
            if (dA) uA0 = *(const uint4*)(g8 + (size_t)a0 * DIM + gg * 16);
            if (dB) uB0 = *(const uint4*)(g8 + (size_t)b0 * DIM + gg * 16);
            if (dA) acc16(gaA, uA0);
            if (dB) acc16(gaB, uB0);
        }
        // combine halves + write both rows
        #pragma unroll
        for (int i = 0; i < 8; ++i) {
            gaA[i][0] += __shfl_xor(gaA[i][0], 8);
            gaA[i][1] += __shfl_xor(gaA[i][1], 8);
            gaB[i][0] += __shfl_xor(gaB[i][0], 8);
            gaB[i][1] += __shfl_xor(gaB[i][1], 8);
        }
        {
            int d = enA - stA;
            float inv = (d > 0) ? 1.f / (float)d : 0.f;
            v2f w0 = sub ? gaA[4] : gaA[0];
            v2f w1 = sub ? gaA[5] : gaA[1];
            v2f w2 = sub ? gaA[6] : gaA[2];
            v2f w3 = sub ? gaA[7] : gaA[3];
            v8u o;
            o[0] = f2bf(w0[0] * inv); o[1] = f2bf(w0[1] * inv);
            o[2] = f2bf(w1[0] * inv); o[3] = f2bf(w1[1] * inv);
            o[4] = f2bf(w2[0] * inv); o[5] = f2bf(w2[1] * inv);
            o[6] = f2bf(w3[0] * inv); o[7] = f2bf(w3[1] * inv);
            *(v8u*)(Alds + rowA * 256 + ((DIM + gg * 16 + sub * 8) ^ ((rowA & 7) * 8))) = o;
        }
        {
            int d = enB - stB;
            float inv = (d > 0) ? 1.f / (float)d : 0.f;
            v2f w0 = sub ? gaB[4] : gaB[0];
            v2f w1 = sub ? gaB[5] : gaB[1];
            v2f w2 = sub ? gaB[6] : gaB[2];
            v2f w3 = sub ? gaB[7] : gaB[3];
            v8u o;
            o[0] = f2bf(w0[0] * inv); o[1] = f2bf(w0[1] * inv);
            o[2] = f2bf(w1[0] * inv); o[3] = f2bf(w1[1] * inv);
            o[4] = f2bf(w2[0] * inv); o[5] = f2bf(w2[1] * inv);
            o[6] = f2bf(w3[0] * inv); o[7] = f2bf(w3[1] * inv);
            *(v8u*)(Alds + rowB * 256 + ((DIM + gg * 16 + sub * 8) ^ ((rowB & 7) * 8))) = o;
        }
    }
    __syncthreads();
    // ---- MFMA: A from LDS, W fragments streamed from L2 (1KB coalesced per wave-load) ----
    const int m = lane & 15, qd = lane >> 4;
    const int arow = wv * 16 + m;
    v4f acc[NT] = {};
    #pragma unroll
    for (int c = 0; c < 8; ++c) {
        const int koff = c * 32 + qd * 8;
        v8s af = *(const v8s*)(Alds + arow * 256 + (koff ^ ((arow & 7) * 8)));
        #pragma unroll
        for (int t = 0; t < NT; ++t) {
            v8s wf = *(const v8s*)(Wf + ((size_t)((t * 8 + c) * 64 + lane)) * 8);
            acc[t] = __builtin_amdgcn_mfma_f32_16x16x32_bf16(af, wf, acc[t], 0, 0, 0);
        }
    }
    // ---- epilogue ----
    #pragma unroll
    for (int t = 0; t < NT; ++t) {
        int col = t * 16 + m;
        bool colok = (col < outdim);
        float bv = colok ? bias[col] : 0.f;
        #pragma unroll
        for (int r = 0; r < 4; ++r) {
            int nrow = m0 + wv * 16 + qd * 4 + r;
            if (colok && nrow < N_NODES) {
                float v = acc[t][r] + bv;
                if (RELU) v = fmaxf(v, 0.f);
                size_t idx = (size_t)nrow * outdim + col;
                if (OUTBF) {
                    ((unsigned short*)out)[idx] = f2bf(v);
                    out8[idx] = f2fp8(v);
                } else {
                    ((float*)out)[idx] = v;
                }
            }
        }
    }
}

extern "C" void kernel_launch(void* const* d_in, const int* in_sizes, int n_in,
                              void* d_out, int out_size, void* d_ws, size_t ws_size,
                              hipStream_t stream) {
    const float* x   = (const float*)d_in[0];
    const int*   src = (const int*)d_in[1];
    const int*   dst = (const int*)d_in[2];
    const float* ws1 = (const float*)d_in[3];
    const float* wn1 = (const float*)d_in[4];
    const float* b1  = (const float*)d_in[5];
    const float* ws2 = (const float*)d_in[6];
    const float* wn2 = (const float*)d_in[7];
    const float* b2  = (const float*)d_in[8];
    const float* ws3 = (const float*)d_in[9];
    const float* wn3 = (const float*)d_in[10];
    const float* b3  = (const float*)d_in[11];

    char* p = (char*)d_ws;
    auto alloc = [&](size_t bytes) { char* r = p; p += (bytes + 255) & ~(size_t)255; return r; };
    int*   row_ptr = (int*)alloc((size_t)(N_NODES + 1) * 4);
    int*   srcs    = (int*)alloc((size_t)N_EDGES * 4);
    unsigned int* packed = (unsigned int*)alloc((size_t)N_EDGES * 4);
    int*   parts   = (int*)alloc((size_t)NBIN * NBK * 4);
    unsigned short* xb  = (unsigned short*)alloc((size_t)N_NODES * DIM * 2);
    unsigned short* h1b = (unsigned short*)alloc((size_t)N_NODES * DIM * 2);
    unsigned short* h2b = (unsigned short*)alloc((size_t)N_NODES * DIM * 2);
    unsigned char*  h8a = (unsigned char*)alloc((size_t)N_NODES * DIM);
    unsigned char*  h8b = (unsigned char*)alloc((size_t)N_NODES * DIM);
    unsigned short* wf1 = (unsigned short*)alloc((size_t)8 * 8 * 64 * 8 * 2);
    unsigned short* wf2 = (unsigned short*)alloc((size_t)8 * 8 * 64 * 8 * 2);
    unsigned short* wf3 = (unsigned short*)alloc((size_t)3 * 8 * 64 * 8 * 2);

    // 1: conversions + bucket hist partials (no global atomics, no memsets)
    k_prep<<<XCVT_NB + NBIN + WFNB, 256, 0, stream>>>(
        x, xb, (unsigned int*)h8a, dst, parts,
        ws1, wn1, ws2, wn2, ws3, wn3, wf1, wf2, wf3);
    // 2-3: CSR (bucket prefix recomputed locally in each kernel; no serial scan dispatch)
    k_bin<<<NBIN, 256, 0, stream>>>(src, dst, parts, packed);
    k_place<<<NBK, 256, 0, stream>>>(packed, parts, row_ptr, srcs);

    const int MB = (N_NODES + 63) / 64; // 782

    // fused layers: agg + GEMM in one kernel each; fp8 table ping-pongs h8a <-> h8b
    k_layer<8, true, true><<<MB, 256, 0, stream>>>(xb,  h8a, row_ptr, srcs, wf1, b1, h1b, h8b, DIM);
    k_layer<8, true, true><<<MB, 256, 0, stream>>>(h1b, h8b, row_ptr, srcs, wf2, b2, h2b, h8a, DIM);
    k_layer<3, false, false><<<MB, 256, 0, stream>>>(h2b, h8a, row_ptr, srcs, wf3, b3, d_out, nullptr, OUTD);
}

// Round 8
// 238.282 us; speedup vs baseline: 2.2942x; 2.2942x over previous
//
#include <hip/hip_runtime.h>

#define N_NODES 50000
#define N_EDGES 800000
#define DIM 128
#define OUTD 47
#define NBK 196                          // dst buckets of 256 nodes
#define EPB 4096                         // edges per histogram/bin block
#define NBIN ((N_EDGES + EPB - 1) / EPB) // 196
#define XCVT_NB (N_NODES * DIM / 8 / 256) // 3125 blocks, 8 elems/thread
#define WFNB 19                          // weight-fragment tiles: 8 + 8 + 3

typedef __attribute__((ext_vector_type(8))) short v8s;
typedef __attribute__((ext_vector_type(8))) unsigned short v8u;
typedef __attribute__((ext_vector_type(4))) float v4f;
typedef __attribute__((ext_vector_type(2))) float v2f;

static __device__ __forceinline__ unsigned short f2bf(float f) {
    union { float f; unsigned int u; } v; v.f = f;
    unsigned int x = v.u;
    return (unsigned short)((x + 0x7fffu + ((x >> 16) & 1u)) >> 16); // RNE
}
static __device__ __forceinline__ unsigned char f2fp8(float f) {
    unsigned int pk = __builtin_amdgcn_cvt_pk_fp8_f32(f, f, 0, false);
    return (unsigned char)(pk & 0xffu);
}

// ---------------- prep: x->bf16+fp8 | per-block bucket hist partials | weight fragment cvt ----------------
// Weights are emitted PRE-SWIZZLED into MFMA B-fragment order:
//   frag(t, c): lane l holds W[j = t*16 + (l&15)][k = c*32 + (l>>4)*8 + i], i=0..7 (bf16 x8, 16B)
//   stored at ob[((t*8 + c)*64 + l)*8 + i]  -> a wave's fragment read is 1KB contiguous.
__global__ __launch_bounds__(256) void k_prep(const float* __restrict__ x,
                                              unsigned short* __restrict__ xb,
                                              unsigned int* __restrict__ x8,
                                              const int* __restrict__ dst,
                                              int* __restrict__ parts,
                                              const float* __restrict__ ws1, const float* __restrict__ wn1,
                                              const float* __restrict__ ws2, const float* __restrict__ wn2,
                                              const float* __restrict__ ws3, const float* __restrict__ wn3,
                                              unsigned short* __restrict__ wf1,
                                              unsigned short* __restrict__ wf2,
                                              unsigned short* __restrict__ wf3) {
    __shared__ int hist[NBK];
    const int bx = blockIdx.x, tid = threadIdx.x;
    if (bx < XCVT_NB) {
        int i = bx * 256 + tid; // 8 elems per thread
        float4 v0 = ((const float4*)x)[i * 2];
        float4 v1 = ((const float4*)x)[i * 2 + 1];
        ushort4 o0, o1;
        o0.x = f2bf(v0.x); o0.y = f2bf(v0.y); o0.z = f2bf(v0.z); o0.w = f2bf(v0.w);
        o1.x = f2bf(v1.x); o1.y = f2bf(v1.y); o1.z = f2bf(v1.z); o1.w = f2bf(v1.w);
        ((ushort4*)xb)[i * 2] = o0;
        ((ushort4*)xb)[i * 2 + 1] = o1;
        unsigned int a = __builtin_amdgcn_cvt_pk_fp8_f32(v0.x, v0.y, 0, false);
        a = __builtin_amdgcn_cvt_pk_fp8_f32(v0.z, v0.w, a, true);
        unsigned int b = __builtin_amdgcn_cvt_pk_fp8_f32(v1.x, v1.y, 0, false);
        b = __builtin_amdgcn_cvt_pk_fp8_f32(v1.z, v1.w, b, true);
        uint2 o; o.x = a; o.y = b;
        ((uint2*)x8)[i] = o;
    } else if (bx < XCVT_NB + NBIN) {
        const int j = bx - XCVT_NB;
        for (int i = tid; i < NBK; i += 256) hist[i] = 0;
        __syncthreads();
        const int e0 = j * EPB;
        const int ecnt = min(EPB, N_EDGES - e0);
        for (int r = tid; r < ecnt; r += 256)
            atomicAdd(&hist[dst[e0 + r] >> 8], 1); // LDS only
        __syncthreads();
        for (int i = tid; i < NBK; i += 256) parts[j * NBK + i] = hist[i];
    } else {
        int b2 = bx - XCVT_NB - NBIN; // fragment tile
        const float *sw, *nw; unsigned short* ob; int t, J;
        if (b2 < 8)       { sw = ws1; nw = wn1; ob = wf1; t = b2;      J = DIM; }
        else if (b2 < 16) { sw = ws2; nw = wn2; ob = wf2; t = b2 - 8;  J = DIM; }
        else              { sw = ws3; nw = wn3; ob = wf3; t = b2 - 16; J = OUTD; }
        const int lane = tid & 63, cp = tid >> 6;
        const int j = t * 16 + (lane & 15);
        const int kb = (lane >> 4) * 8;
        #pragma unroll
        for (int c2 = 0; c2 < 2; ++c2) {
            int c = cp * 2 + c2;
            int k0 = c * 32 + kb;
            v8u o;
            #pragma unroll
            for (int i = 0; i < 8; ++i) {
                int k = k0 + i;
                float v = 0.f;
                if (j < J) v = (k < DIM) ? sw[j * DIM + k] : nw[j * DIM + (k - DIM)];
                o[i] = f2bf(v);
            }
            *(v8u*)(ob + ((size_t)((t * 8 + c) * 64 + lane)) * 8) = o;
        }
    }
}

// ---------------- bin: local column-prefix of parts -> bases; place edges (LDS atomics only) ----------------
__global__ __launch_bounds__(256) void k_bin(const int* __restrict__ src,
                                             const int* __restrict__ dst,
                                             const int* __restrict__ parts,
                                             unsigned int* __restrict__ packed) {
    __shared__ int s[256], gb[NBK], cnt[NBK];
    const int t = threadIdx.x;
    const int j = blockIdx.x;
    int ct = 0, cp = 0;
    for (int i = 0; i < NBIN; ++i) {
        int v = (t < NBK) ? parts[i * NBK + t] : 0;
        if (i == j) cp = ct;
        ct += v;
    }
    s[t] = ct;
    __syncthreads();
    for (int off = 1; off < 256; off <<= 1) {
        int u = (t >= off) ? s[t - off] : 0;
        __syncthreads();
        s[t] += u;
        __syncthreads();
    }
    if (t < NBK) { gb[t] = (s[t] - ct) + cp; cnt[t] = 0; } // bucket base + own-block offset
    __syncthreads();
    const int e0 = j * EPB;
    const int ecnt = min(EPB, N_EDGES - e0);
    for (int r = t; r < ecnt; r += 256) {
        int sv = src[e0 + r], d = dst[e0 + r];
        int b = d >> 8;
        int loc = atomicAdd(&cnt[b], 1); // LDS
        packed[gb[b] + loc] = ((unsigned int)sv << 8) | (unsigned int)(d & 255);
    }
}

// ---------------- place: local bucket scan + per-node hist -> row_ptr, scatter src_sorted ----------------
__global__ __launch_bounds__(256) void k_place(const unsigned int* __restrict__ packed,
                                               const int* __restrict__ parts,
                                               int* __restrict__ row_ptr,
                                               int* __restrict__ src_sorted) {
    __shared__ int s[256], baseL[NBK], totL[NBK];
    __shared__ int hist[256], cur[256];
    const int b = blockIdx.x, t = threadIdx.x;
    int ct = 0;
    for (int i = 0; i < NBIN; ++i)
        ct += (t < NBK) ? parts[i * NBK + t] : 0;
    s[t] = ct;
    hist[t] = 0;
    __syncthreads();
    for (int off = 1; off < 256; off <<= 1) {
        int u = (t >= off) ? s[t - off] : 0;
        __syncthreads();
        s[t] += u;
        __syncthreads();
    }
    if (t < NBK) { baseL[t] = s[t] - ct; totL[t] = ct; }
    __syncthreads();
    const int base = baseL[b], cb = totL[b];
    for (int i = t; i < cb; i += 256)
        atomicAdd(&hist[packed[base + i] & 255u], 1); // LDS, ~16 avg per counter
    __syncthreads();
    int v = hist[t];
    s[t] = v;
    __syncthreads();
    for (int off = 1; off < 256; off <<= 1) {
        int u = (t >= off) ? s[t - off] : 0;
        __syncthreads();
        s[t] += u;
        __syncthreads();
    }
    int excl = base + s[t] - v;
    int node = b * 256 + t;
    if (node < N_NODES) row_ptr[node] = excl;
    if (b == NBK - 1 && t == 255) row_ptr[N_NODES] = base + cb; // == N_EDGES
    cur[t] = excl;
    __syncthreads();
    for (int i = t; i < cb; i += 256) {
        unsigned int pkt = packed[base + i];
        int pos = atomicAdd(&cur[pkt & 255u], 1);
        src_sorted[pos] = (int)(pkt >> 8); // lands in this bucket's ~16KB region
    }
}

// ---------------- fused layer: self-load + mean-aggregate -> LDS A-tile, then MFMA GEMM ----------------
// R3 structure (verified 241.5us). R5's dual-chain spilled to scratch (282MB writes/dispatch,
// VGPR capped at 64) -- reverted. MLP improvement kept register-light instead: prefetch the NEXT
// iteration's 4 src indices before accumulating the current gathers (+4 int regs only), so the
// srcs ~200cy L2 latency hides under the current iteration's gather consumption.
static __device__ __forceinline__ void acc16(v2f* acc, uint4 u) {
    acc[0] += __builtin_amdgcn_cvt_pk_f32_fp8(u.x, false);
    acc[1] += __builtin_amdgcn_cvt_pk_f32_fp8(u.x, true);
    acc[2] += __builtin_amdgcn_cvt_pk_f32_fp8(u.y, false);
    acc[3] += __builtin_amdgcn_cvt_pk_f32_fp8(u.y, true);
    acc[4] += __builtin_amdgcn_cvt_pk_f32_fp8(u.z, false);
    acc[5] += __builtin_amdgcn_cvt_pk_f32_fp8(u.z, true);
    acc[6] += __builtin_amdgcn_cvt_pk_f32_fp8(u.w, false);
    acc[7] += __builtin_amdgcn_cvt_pk_f32_fp8(u.w, true);
}

template <int NT, bool RELU, bool OUTBF>
__global__ __launch_bounds__(256, 4) void k_layer(const unsigned short* __restrict__ Ab,
                                                  const unsigned char* __restrict__ g8,
                                                  const int* __restrict__ row_ptr,
                                                  const int* __restrict__ srcs,
                                                  const unsigned short* __restrict__ Wf,
                                                  const float* __restrict__ bias,
                                                  void* __restrict__ out,
                                                  unsigned char* __restrict__ out8,
                                                  int outdim) {
    __shared__ unsigned short Alds[64 * 256]; // 32 KB: [row][0..128)=self, [128..256)=mean, XOR-swizzled
    const int tid = threadIdx.x;
    const int m0 = blockIdx.x * 64;
    // ---- self half -> LDS ----
    #pragma unroll
    for (int i = 0; i < 4; ++i) {
        int t = tid + 256 * i;           // 0..1023
        int row = t >> 4, ch = t & 15;   // 64 rows x 16 chunks of 8 shorts
        int node = m0 + row; if (node >= N_NODES) node = N_NODES - 1;
        v8u v = *(const v8u*)(Ab + (size_t)node * DIM + ch * 8);
        *(v8u*)(Alds + row * 256 + ((ch * 8) ^ ((row & 7) * 8))) = v;
    }
    // ---- mean half: gather fp8 rows, 4 nodes per wave-pass, 2x8-lane halves per node ----
    const int lane = tid & 63, wv = tid >> 6;
    const int gg = lane & 7;          // 8 lanes span the 128B row, 16B each
    const int sub = (lane >> 3) & 1;  // which edge of a pair this half handles
    const int ns = lane >> 4;         // node slot within wave
    for (int pass = 0; pass < 4; ++pass) {
        const int row = wv * 16 + pass * 4 + ns; // 0..63
        const int n = m0 + row;
        int start = 0, end = 0;
        if (n < N_NODES) { start = row_ptr[n]; end = row_ptr[n + 1]; }
        v2f ga[8] = {};
        int e = start;
        int s0, s1, s2, s3;
        bool have = (e + 8 <= end);
        if (have) {
            s0 = srcs[e + sub]; s1 = srcs[e + 2 + sub];
            s2 = srcs[e + 4 + sub]; s3 = srcs[e + 6 + sub];
        }
        while (have) {
            uint4 u0 = *(const uint4*)(g8 + (size_t)s0 * DIM + gg * 16);
            uint4 u1 = *(const uint4*)(g8 + (size_t)s1 * DIM + gg * 16);
            uint4 u2 = *(const uint4*)(g8 + (size_t)s2 * DIM + gg * 16);
            uint4 u3 = *(const uint4*)(g8 + (size_t)s3 * DIM + gg * 16);
            e += 8;
            have = (e + 8 <= end);
            if (have) { // prefetch next indices while gathers are in flight
                s0 = srcs[e + sub]; s1 = srcs[e + 2 + sub];
                s2 = srcs[e + 4 + sub]; s3 = srcs[e + 6 + sub];
            }
            acc16(ga, u0); acc16(ga, u1); acc16(ga, u2); acc16(ga, u3);
        }
        if (e + 4 <= end) {
            int t0 = srcs[e + sub], t1 = srcs[e + 2 + sub];
            uint4 u0 = *(const uint4*)(g8 + (size_t)t0 * DIM + gg * 16);
            uint4 u1 = *(const uint4*)(g8 + (size_t)t1 * DIM + gg * 16);
            acc16(ga, u0); acc16(ga, u1);
            e += 4;
        }
        if (e + 2 <= end) {
            int t0 = srcs[e + sub];
            uint4 u0 = *(const uint4*)(g8 + (size_t)t0 * DIM + gg * 16);
            acc16(ga, u0);
            e += 2;
        }
        if (e < end && sub == 0) { // odd leftover edge: even half only
            int t0 = srcs[e];
            uint4 u0 = *(const uint4*)(g8 + (size_t)t0 * DIM + gg * 16);
            acc16(ga, u0);
        }
        #pragma unroll
        for (int i = 0; i < 8; ++i) {
            ga[i][0] += __shfl_xor(ga[i][0], 8);
            ga[i][1] += __shfl_xor(ga[i][1], 8);
        }
        int d = end - start;
        float inv = (d > 0) ? 1.f / (float)d : 0.f;
        v2f w0 = sub ? ga[4] : ga[0];
        v2f w1 = sub ? ga[5] : ga[1];
        v2f w2 = sub ? ga[6] : ga[2];
        v2f w3 = sub ? ga[7] : ga[3];
        v8u o;
        o[0] = f2bf(w0[0] * inv); o[1] = f2bf(w0[1] * inv);
        o[2] = f2bf(w1[0] * inv); o[3] = f2bf(w1[1] * inv);
        o[4] = f2bf(w2[0] * inv); o[5] = f2bf(w2[1] * inv);
        o[6] = f2bf(w3[0] * inv); o[7] = f2bf(w3[1] * inv);
        *(v8u*)(Alds + row * 256 + ((DIM + gg * 16 + sub * 8) ^ ((row & 7) * 8))) = o;
    }
    __syncthreads();
    // ---- MFMA: A from LDS, W fragments streamed from L2 (1KB coalesced per wave-load) ----
    const int m = lane & 15, qd = lane >> 4;
    const int arow = wv * 16 + m;
    v4f acc[NT] = {};
    #pragma unroll
    for (int c = 0; c < 8; ++c) {
        const int koff = c * 32 + qd * 8;
        v8s af = *(const v8s*)(Alds + arow * 256 + (koff ^ ((arow & 7) * 8)));
        #pragma unroll
        for (int t = 0; t < NT; ++t) {
            v8s wf = *(const v8s*)(Wf + ((size_t)((t * 8 + c) * 64 + lane)) * 8);
            acc[t] = __builtin_amdgcn_mfma_f32_16x16x32_bf16(af, wf, acc[t], 0, 0, 0);
        }
    }
    // ---- epilogue ----
    #pragma unroll
    for (int t = 0; t < NT; ++t) {
        int col = t * 16 + m;
        bool colok = (col < outdim);
        float bv = colok ? bias[col] : 0.f;
        #pragma unroll
        for (int r = 0; r < 4; ++r) {
            int nrow = m0 + wv * 16 + qd * 4 + r;
            if (colok && nrow < N_NODES) {
                float v = acc[t][r] + bv;
                if (RELU) v = fmaxf(v, 0.f);
                size_t idx = (size_t)nrow * outdim + col;
                if (OUTBF) {
                    ((unsigned short*)out)[idx] = f2bf(v);
                    out8[idx] = f2fp8(v);
                } else {
                    ((float*)out)[idx] = v;
                }
            }
        }
    }
}

extern "C" void kernel_launch(void* const* d_in, const int* in_sizes, int n_in,
                              void* d_out, int out_size, void* d_ws, size_t ws_size,
                              hipStream_t stream) {
    const float* x   = (const float*)d_in[0];
    const int*   src = (const int*)d_in[1];
    const int*   dst = (const int*)d_in[2];
    const float* ws1 = (const float*)d_in[3];
    const float* wn1 = (const float*)d_in[4];
    const float* b1  = (const float*)d_in[5];
    const float* ws2 = (const float*)d_in[6];
    const float* wn2 = (const float*)d_in[7];
    const float* b2  = (const float*)d_in[8];
    const float* ws3 = (const float*)d_in[9];
    const float* wn3 = (const float*)d_in[10];
    const float* b3  = (const float*)d_in[11];

    char* p = (char*)d_ws;
    auto alloc = [&](size_t bytes) { char* r = p; p += (bytes + 255) & ~(size_t)255; return r; };
    int*   row_ptr = (int*)alloc((size_t)(N_NODES + 1) * 4);
    int*   srcs    = (int*)alloc((size_t)N_EDGES * 4);
    unsigned int* packed = (unsigned int*)alloc((size_t)N_EDGES * 4);
    int*   parts   = (int*)alloc((size_t)NBIN * NBK * 4);
    unsigned short* xb  = (unsigned short*)alloc((size_t)N_NODES * DIM * 2);
    unsigned short* h1b = (unsigned short*)alloc((size_t)N_NODES * DIM * 2);
    unsigned short* h2b = (unsigned short*)alloc((size_t)N_NODES * DIM * 2);
    unsigned char*  h8a = (unsigned char*)alloc((size_t)N_NODES * DIM);
    unsigned char*  h8b = (unsigned char*)alloc((size_t)N_NODES * DIM);
    unsigned short* wf1 = (unsigned short*)alloc((size_t)8 * 8 * 64 * 8 * 2);
    unsigned short* wf2 = (unsigned short*)alloc((size_t)8 * 8 * 64 * 8 * 2);
    unsigned short* wf3 = (unsigned short*)alloc((size_t)3 * 8 * 64 * 8 * 2);

    // 1: conversions + bucket hist partials (no global atomics, no memsets)
    k_prep<<<XCVT_NB + NBIN + WFNB, 256, 0, stream>>>(
        x, xb, (unsigned int*)h8a, dst, parts,
        ws1, wn1, ws2, wn2, ws3, wn3, wf1, wf2, wf3);
    // 2-3: CSR (bucket prefix recomputed locally in each kernel; no serial scan dispatch)
    k_bin<<<NBIN, 256, 0, stream>>>(src, dst, parts, packed);
    k_place<<<NBK, 256, 0, stream>>>(packed, parts, row_ptr, srcs);

    const int MB = (N_NODES + 63) / 64; // 782

    // fused layers: agg + GEMM in one kernel each; fp8 table ping-pongs h8a <-> h8b
    k_layer<8, true, true><<<MB, 256, 0, stream>>>(xb,  h8a, row_ptr, srcs, wf1, b1, h1b, h8b, DIM);
    k_layer<8, true, true><<<MB, 256, 0, stream>>>(h1b, h8b, row_ptr, srcs, wf2, b2, h2b, h8a, DIM);
    k_layer<3, false, false><<<MB, 256, 0, stream>>>(h2b, h8a, row_ptr, srcs, wf3, b3, d_out, nullptr, OUTD);
}